// Round 1
// baseline (314.112 us; speedup 1.0000x reference)
//
#include <hip/hip_runtime.h>
#include <stdint.h>

typedef unsigned short ushort_t;
typedef __attribute__((ext_vector_type(8))) short short8;
typedef __attribute__((ext_vector_type(4))) float f32x4;

#define NSEQ 2048
#define BSZ 8
#define EMB 512
#define NHEAD 8
#define HDIM 64
#define MTOK (NSEQ*BSZ)      // 16384
#define NH_TOT (BSZ*NHEAD)   // 64

__device__ __forceinline__ ushort_t f2bf(float f) {
  uint32_t u = __builtin_bit_cast(uint32_t, f);
  u += 0x7FFFu + ((u >> 16) & 1u);
  return (ushort_t)(u >> 16);
}
__device__ __forceinline__ float bf2f(ushort_t u) {
  uint32_t x = ((uint32_t)u) << 16;
  return __builtin_bit_cast(float, x);
}

__device__ __forceinline__ void gll16(const void* g, void* l) {
  __builtin_amdgcn_global_load_lds(
      (const __attribute__((address_space(1))) void*)g,
      (__attribute__((address_space(3))) void*)l, 16, 0, 0);
}

// ---------------- f32 -> bf16 convert ----------------
__global__ void cvt_f32_bf16(const float* __restrict__ in, ushort_t* __restrict__ out, int n4) {
  int i = blockIdx.x * blockDim.x + threadIdx.x;
  if (i >= n4) return;
  float4 v = reinterpret_cast<const float4*>(in)[i];
  union { ushort_t u[4]; uint64_t q; } o;
  o.u[0] = f2bf(v.x); o.u[1] = f2bf(v.y); o.u[2] = f2bf(v.z); o.u[3] = f2bf(v.w);
  reinterpret_cast<uint64_t*>(out)[i] = o.q;
}

// ---------------- GEMM: C[M,N] = A[M,K] * B[N,K]^T + bias ----------------
// MODE 0: epilogue scatters bf16 into q/k/v per-head buffers [3][64][2048][64]
// MODE 1: epilogue writes f32 to Cf
template<int MODE>
__global__ __launch_bounds__(256) void gemm_bt(
    const ushort_t* __restrict__ A, const ushort_t* __restrict__ B,
    const float* __restrict__ bias,
    float* __restrict__ Cf, ushort_t* __restrict__ Cq,
    int M, int N, int K)
{
  __shared__ __align__(16) ushort_t As[128*64];
  __shared__ __align__(16) ushort_t Bs[128*64];
  const int t = threadIdx.x;
  const int w = t >> 6, l = t & 63;
  const int tm = blockIdx.y * 128, tn = blockIdx.x * 128;
  const int wm = w >> 1, wn = w & 1;

  f32x4 acc[4][4] = {};

  for (int k0 = 0; k0 < K; k0 += 64) {
    // stage A and B tiles (128x64 bf16 each) via global_load_lds,
    // pre-swizzled global source so LDS holds XOR-swizzled layout
    #pragma unroll
    for (int j = 0; j < 4; ++j) {
      int row = j*32 + w*8 + (l >> 3);
      int cole = ((l & 7) * 8) ^ ((row & 7) << 3);   // element offset within 64
      const ushort_t* ga = A + (size_t)(tm + row) * K + k0 + cole;
      const ushort_t* gb = B + (size_t)(tn + row) * K + k0 + cole;
      ushort_t* la = As + j*2048 + w*512;
      ushort_t* lb = Bs + j*2048 + w*512;
      gll16(ga, la);
      gll16(gb, lb);
    }
    __syncthreads();
    #pragma unroll
    for (int kk = 0; kk < 2; ++kk) {
      short8 af[4], bfr[4];
      #pragma unroll
      for (int mi = 0; mi < 4; ++mi) {
        int row = wm*64 + mi*16 + (l & 15);
        int byte = row*128 + ((kk*64 + ((l >> 4) * 16)) ^ ((row & 7) << 4));
        af[mi] = *reinterpret_cast<const short8*>(reinterpret_cast<const char*>(As) + byte);
      }
      #pragma unroll
      for (int ni = 0; ni < 4; ++ni) {
        int row = wn*64 + ni*16 + (l & 15);
        int byte = row*128 + ((kk*64 + ((l >> 4) * 16)) ^ ((row & 7) << 4));
        bfr[ni] = *reinterpret_cast<const short8*>(reinterpret_cast<const char*>(Bs) + byte);
      }
      #pragma unroll
      for (int mi = 0; mi < 4; ++mi)
        #pragma unroll
        for (int ni = 0; ni < 4; ++ni)
          acc[mi][ni] = __builtin_amdgcn_mfma_f32_16x16x32_bf16(af[mi], bfr[ni], acc[mi][ni], 0, 0, 0);
    }
    __syncthreads();
  }

  #pragma unroll
  for (int mi = 0; mi < 4; ++mi) {
    #pragma unroll
    for (int ni = 0; ni < 4; ++ni) {
      #pragma unroll
      for (int r = 0; r < 4; ++r) {
        int row = tm + wm*64 + mi*16 + ((l >> 4) * 4) + r;
        int col = tn + wn*64 + ni*16 + (l & 15);
        float v = acc[mi][ni][r] + bias[col];
        if constexpr (MODE == 1) {
          Cf[(size_t)row * N + col] = v;
        } else {
          int w3 = col >> 9, h = (col >> 6) & 7, hd = col & 63;
          int n = row >> 3, b = row & 7;
          Cq[(size_t)w3 * ((size_t)NH_TOT * NSEQ * HDIM)
             + ((size_t)(b * NHEAD + h) * NSEQ + n) * HDIM + hd] = f2bf(v);
        }
      }
    }
  }
}

// ---------------- Flash attention ----------------
// Q/K/V: [64 heads][2048][64] bf16. Output Ob: [16384 rows = n*8+b][512 = h*64+hd] bf16.
__global__ __launch_bounds__(256) void attn_fwd(
    const ushort_t* __restrict__ Qb, const ushort_t* __restrict__ Kb,
    const ushort_t* __restrict__ Vb, ushort_t* __restrict__ Ob)
{
  __shared__ __align__(16) ushort_t Ks[64*64];
  __shared__ __align__(16) ushort_t Vt[64*64];
  __shared__ __align__(16) ushort_t Ps[4*32*64];
  const int t = threadIdx.x, w = t >> 6, l = t & 63;
  const int bh = blockIdx.y;               // 0..63 (= b*8 + h)
  const int qt = blockIdx.x;               // 0..15
  const int b = bh >> 3, h = bh & 7;
  const size_t hbase = (size_t)bh * NSEQ * HDIM;
  const int qbase = qt * 128 + w * 32;

  // Q fragments, pre-scaled by 1/8 (exact: power of two)
  short8 qf[2][2];
  #pragma unroll
  for (int mt = 0; mt < 2; ++mt)
    #pragma unroll
    for (int kf = 0; kf < 2; ++kf) {
      int n = qbase + mt*16 + (l & 15);
      int d = kf*32 + ((l >> 4) * 8);
      short8 raw = *reinterpret_cast<const short8*>(Qb + hbase + (size_t)n * HDIM + d);
      short8 q;
      #pragma unroll
      for (int e = 0; e < 8; ++e)
        q[e] = (short)f2bf(bf2f((ushort_t)raw[e]) * 0.125f);
      qf[mt][kf] = q;
    }

  float m_run[2][4], l_run[2][4];
  f32x4 Oacc[2][4] = {};
  #pragma unroll
  for (int mt = 0; mt < 2; ++mt)
    #pragma unroll
    for (int r = 0; r < 4; ++r) { m_run[mt][r] = -1e30f; l_run[mt][r] = 0.f; }

  for (int kt = 0; kt < NSEQ/64; ++kt) {
    const size_t kvbase = hbase + (size_t)kt * 64 * HDIM;
    // stage K (row-swizzled) and V^T (d-swizzled with (d>>3)^d mask)
    #pragma unroll
    for (int j = 0; j < 2; ++j) {
      int idx = j*2048 + t*8;
      int row = idx >> 6;            // 0..63
      int d0  = idx & 63;            // multiple of 8
      short8 kraw = *reinterpret_cast<const short8*>(Kb + kvbase + (size_t)row*HDIM + d0);
      int kbyte = row*128 + ((d0*2) ^ ((row & 7) << 4));
      *reinterpret_cast<short8*>(reinterpret_cast<char*>(Ks) + kbyte) = kraw;
      short8 vraw = *reinterpret_cast<const short8*>(Vb + kvbase + (size_t)row*HDIM + d0);
      #pragma unroll
      for (int e = 0; e < 8; ++e) {
        int d = d0 + e;
        int vbyte = d*128 + ((row*2) ^ ((((d >> 3) ^ d) & 7) << 4));
        *reinterpret_cast<ushort_t*>(reinterpret_cast<char*>(Vt) + vbyte) = (ushort_t)vraw[e];
      }
    }
    __syncthreads();

    // S = (Q/8) K^T  : per wave 32x64
    short8 kfr[4][2];
    #pragma unroll
    for (int c = 0; c < 4; ++c)
      #pragma unroll
      for (int kf = 0; kf < 2; ++kf) {
        int kvrow = c*16 + (l & 15);
        int byte = kvrow*128 + ((kf*64 + ((l >> 4) * 16)) ^ ((kvrow & 7) << 4));
        kfr[c][kf] = *reinterpret_cast<const short8*>(reinterpret_cast<const char*>(Ks) + byte);
      }
    f32x4 s[2][4] = {};
    #pragma unroll
    for (int mt = 0; mt < 2; ++mt)
      #pragma unroll
      for (int c = 0; c < 4; ++c)
        #pragma unroll
        for (int kf = 0; kf < 2; ++kf)
          s[mt][c] = __builtin_amdgcn_mfma_f32_16x16x32_bf16(qf[mt][kf], kfr[c][kf], s[mt][c], 0, 0, 0);

    // online softmax per row (rows live in 16-lane groups, reg r = row (g*4+r))
    #pragma unroll
    for (int mt = 0; mt < 2; ++mt) {
      float mnew[4], corr[4], psum[4];
      #pragma unroll
      for (int r = 0; r < 4; ++r) {
        float mx = fmaxf(fmaxf(s[mt][0][r], s[mt][1][r]), fmaxf(s[mt][2][r], s[mt][3][r]));
        mx = fmaxf(mx, __shfl_xor(mx, 1));
        mx = fmaxf(mx, __shfl_xor(mx, 2));
        mx = fmaxf(mx, __shfl_xor(mx, 4));
        mx = fmaxf(mx, __shfl_xor(mx, 8));
        mnew[r] = fmaxf(m_run[mt][r], mx);
        corr[r] = __expf(m_run[mt][r] - mnew[r]);
        m_run[mt][r] = mnew[r];
        l_run[mt][r] *= corr[r];
      }
      #pragma unroll
      for (int dt = 0; dt < 4; ++dt)
        #pragma unroll
        for (int r = 0; r < 4; ++r)
          Oacc[mt][dt][r] *= corr[r];
      #pragma unroll
      for (int r = 0; r < 4; ++r) psum[r] = 0.f;
      #pragma unroll
      for (int c = 0; c < 4; ++c)
        #pragma unroll
        for (int r = 0; r < 4; ++r) {
          float p = __expf(s[mt][c][r] - m_run[mt][r]);
          s[mt][c][r] = p;
          psum[r] += p;
        }
      #pragma unroll
      for (int r = 0; r < 4; ++r) {
        float ps = psum[r];
        ps += __shfl_xor(ps, 1); ps += __shfl_xor(ps, 2);
        ps += __shfl_xor(ps, 4); ps += __shfl_xor(ps, 8);
        l_run[mt][r] += ps;
      }
      // write P (bf16) to per-wave swizzled LDS buffer
      #pragma unroll
      for (int c = 0; c < 4; ++c)
        #pragma unroll
        for (int r = 0; r < 4; ++r) {
          int row = mt*16 + ((l >> 4) * 4) + r;
          int col = c*16 + (l & 15);
          int byte = row*128 + ((col*2) ^ ((row & 7) << 4));
          *reinterpret_cast<ushort_t*>(reinterpret_cast<char*>(Ps) + w*4096 + byte) = f2bf(s[mt][c][r]);
        }
    }

    // O += P V
    short8 vfr[4][2];
    #pragma unroll
    for (int dt = 0; dt < 4; ++dt)
      #pragma unroll
      for (int kf = 0; kf < 2; ++kf) {
        int d = dt*16 + (l & 15);
        int byte = d*128 + ((kf*64 + ((l >> 4) * 16)) ^ ((((d >> 3) ^ d) & 7) << 4));
        vfr[dt][kf] = *reinterpret_cast<const short8*>(reinterpret_cast<const char*>(Vt) + byte);
      }
    short8 paf[2][2];
    #pragma unroll
    for (int mt = 0; mt < 2; ++mt)
      #pragma unroll
      for (int kf = 0; kf < 2; ++kf) {
        int row = mt*16 + (l & 15);
        int byte = row*128 + ((kf*64 + ((l >> 4) * 16)) ^ ((row & 7) << 4));
        paf[mt][kf] = *reinterpret_cast<const short8*>(reinterpret_cast<const char*>(Ps) + w*4096 + byte);
      }
    #pragma unroll
    for (int mt = 0; mt < 2; ++mt)
      #pragma unroll
      for (int dt = 0; dt < 4; ++dt)
        #pragma unroll
        for (int kf = 0; kf < 2; ++kf)
          Oacc[mt][dt] = __builtin_amdgcn_mfma_f32_16x16x32_bf16(paf[mt][kf], vfr[dt][kf], Oacc[mt][dt], 0, 0, 0);
    __syncthreads();
  }

  // epilogue: O /= l, write bf16 rows (n*8+b, h*64+hd)
  #pragma unroll
  for (int mt = 0; mt < 2; ++mt)
    #pragma unroll
    for (int dt = 0; dt < 4; ++dt)
      #pragma unroll
      for (int r = 0; r < 4; ++r) {
        int n = qbase + mt*16 + ((l >> 4) * 4) + r;
        int e = h*64 + dt*16 + (l & 15);
        float v = Oacc[mt][dt][r] / l_run[mt][r];
        Ob[((size_t)n * BSZ + b) * EMB + e] = f2bf(v);
      }
}

extern "C" void kernel_launch(void* const* d_in, const int* in_sizes, int n_in,
                              void* d_out, int out_size, void* d_ws, size_t ws_size,
                              hipStream_t stream) {
  (void)in_sizes; (void)n_in; (void)out_size; (void)ws_size;
  const float* seq  = (const float*)d_in[0];
  const float* Wqkv = (const float*)d_in[1];
  const float* bqkv = (const float*)d_in[2];
  const float* Wout = (const float*)d_in[3];
  const float* bout = (const float*)d_in[4];
  float* out = (float*)d_out;

  ushort_t* seq_bf  = (ushort_t*)d_ws;                            // 16 MB
  ushort_t* wqkv_bf = seq_bf  + (size_t)MTOK * EMB;               // 1.5 MB
  ushort_t* wout_bf = wqkv_bf + (size_t)3 * EMB * EMB;            // 0.5 MB
  ushort_t* qkvbuf  = wout_bf + (size_t)EMB * EMB;                // 48 MB (q,k,v)
  ushort_t* attno   = qkvbuf  + (size_t)3 * NH_TOT * NSEQ * HDIM; // 16 MB

  cvt_f32_bf16<<<(MTOK*EMB/4 + 255)/256, 256, 0, stream>>>(seq, seq_bf, MTOK*EMB/4);
  cvt_f32_bf16<<<(3*EMB*EMB/4 + 255)/256, 256, 0, stream>>>(Wqkv, wqkv_bf, 3*EMB*EMB/4);
  cvt_f32_bf16<<<(EMB*EMB/4 + 255)/256, 256, 0, stream>>>(Wout, wout_bf, EMB*EMB/4);

  gemm_bt<0><<<dim3(12, 128), 256, 0, stream>>>(seq_bf, wqkv_bf, bqkv, nullptr, qkvbuf,
                                                MTOK, 3*EMB, EMB);

  const ushort_t* Qb = qkvbuf;
  const ushort_t* Kb = qkvbuf + (size_t)NH_TOT * NSEQ * HDIM;
  const ushort_t* Vb = Kb     + (size_t)NH_TOT * NSEQ * HDIM;
  attn_fwd<<<dim3(16, 64), 256, 0, stream>>>(Qb, Kb, Vb, attno);

  gemm_bt<1><<<dim3(4, 128), 256, 0, stream>>>(attno, wout_bf, bout, out, nullptr,
                                               MTOK, EMB, EMB);
}

// Round 2
// 205.117 us; speedup vs baseline: 1.5314x; 1.5314x over previous
//
#include <hip/hip_runtime.h>
#include <stdint.h>

typedef unsigned short ushort_t;
typedef unsigned int uint32;
typedef __attribute__((ext_vector_type(8))) short short8;
typedef __attribute__((ext_vector_type(4))) float f32x4;
typedef __attribute__((ext_vector_type(16))) float f32x16;
typedef __attribute__((ext_vector_type(4))) uint32 uint4v;

#define NSEQ 2048
#define BSZ 8
#define EMB 512
#define NHEAD 8
#define HDIM 64
#define MTOK (NSEQ*BSZ)      // 16384
#define NH_TOT (BSZ*NHEAD)   // 64

__device__ __forceinline__ ushort_t f2bf(float f) {
  uint32_t u = __builtin_bit_cast(uint32_t, f);
  u += 0x7FFFu + ((u >> 16) & 1u);
  return (ushort_t)(u >> 16);
}

__device__ __forceinline__ void gll16(const void* g, void* l) {
  __builtin_amdgcn_global_load_lds(
      (const __attribute__((address_space(1))) void*)g,
      (__attribute__((address_space(3))) void*)l, 16, 0, 0);
}

// swizzle slot for row r (8 slots of 16B within a 128B row)
__device__ __forceinline__ int SW(int r) { return (r & 7) ^ ((r >> 3) & 7); }

// ---------------- f32 -> bf16 convert ----------------
__global__ void cvt_f32_bf16(const float* __restrict__ in, ushort_t* __restrict__ out, int n4) {
  int i = blockIdx.x * blockDim.x + threadIdx.x;
  if (i >= n4) return;
  float4 v = reinterpret_cast<const float4*>(in)[i];
  union { ushort_t u[4]; uint64_t q; } o;
  o.u[0] = f2bf(v.x); o.u[1] = f2bf(v.y); o.u[2] = f2bf(v.z); o.u[3] = f2bf(v.w);
  reinterpret_cast<uint64_t*>(out)[i] = o.q;
}

// ---------------- GEMM: C[M,N] = A[M,K] * B[N,K]^T + bias ----------------
template<int MODE>
__global__ __launch_bounds__(256) void gemm_bt(
    const ushort_t* __restrict__ A, const ushort_t* __restrict__ B,
    const float* __restrict__ bias,
    float* __restrict__ Cf, ushort_t* __restrict__ Cq,
    int M, int N, int K)
{
  __shared__ __align__(16) ushort_t As[128*64];
  __shared__ __align__(16) ushort_t Bs[128*64];
  const int t = threadIdx.x;
  const int w = t >> 6, l = t & 63;
  const int tm = blockIdx.y * 128, tn = blockIdx.x * 128;
  const int wm = w >> 1, wn = w & 1;

  f32x4 acc[4][4] = {};

  for (int k0 = 0; k0 < K; k0 += 64) {
    #pragma unroll
    for (int j = 0; j < 4; ++j) {
      int row = j*32 + w*8 + (l >> 3);
      int cole = ((l & 7) * 8) ^ ((row & 7) << 3);
      const ushort_t* ga = A + (size_t)(tm + row) * K + k0 + cole;
      const ushort_t* gb = B + (size_t)(tn + row) * K + k0 + cole;
      gll16(ga, As + j*2048 + w*512 + (l & 63) * 8 - (l & 63) * 8 + (l)*8 - l*8 + (t - j*0)*0 + (j*0));
      // NOTE: dest must be linear in lane order:
      gll16(gb, Bs + j*2048 + w*512 + l*8 - l*8);
    }
    // The two calls above must use proper lane-linear destinations; rewritten below.
    __syncthreads();
    __syncthreads();
    break;
  }
  // (unreachable placeholder removed in real body below)
  (void)acc;
}

// Real GEMM (the template above is unused; kept minimal to avoid accidental use)
template<int MODE>
__global__ __launch_bounds__(256) void gemm_bt2(
    const ushort_t* __restrict__ A, const ushort_t* __restrict__ B,
    const float* __restrict__ bias,
    float* __restrict__ Cf, ushort_t* __restrict__ Cq,
    int M, int N, int K)
{
  __shared__ __align__(16) ushort_t As[128*64];
  __shared__ __align__(16) ushort_t Bs[128*64];
  const int t = threadIdx.x;
  const int w = t >> 6, l = t & 63;
  const int tm = blockIdx.y * 128, tn = blockIdx.x * 128;
  const int wm = w >> 1, wn = w & 1;

  f32x4 acc[4][4] = {};

  for (int k0 = 0; k0 < K; k0 += 64) {
    #pragma unroll
    for (int j = 0; j < 4; ++j) {
      int row = j*32 + w*8 + (l >> 3);
      int cole = ((l & 7) * 8) ^ ((row & 7) << 3);
      const ushort_t* ga = A + (size_t)(tm + row) * K + k0 + cole;
      const ushort_t* gb = B + (size_t)(tn + row) * K + k0 + cole;
      ushort_t* la = As + j*2048 + w*512 + l*8;
      ushort_t* lb = Bs + j*2048 + w*512 + l*8;
      gll16(ga, la - l*8 + l*8);
      gll16(gb, lb);
    }
    __syncthreads();
    #pragma unroll
    for (int kk = 0; kk < 2; ++kk) {
      short8 af[4], bfr[4];
      #pragma unroll
      for (int mi = 0; mi < 4; ++mi) {
        int row = wm*64 + mi*16 + (l & 15);
        int byte = row*128 + ((kk*64 + ((l >> 4) * 16)) ^ ((row & 7) << 4));
        af[mi] = *reinterpret_cast<const short8*>(reinterpret_cast<const char*>(As) + byte);
      }
      #pragma unroll
      for (int ni = 0; ni < 4; ++ni) {
        int row = wn*64 + ni*16 + (l & 15);
        int byte = row*128 + ((kk*64 + ((l >> 4) * 16)) ^ ((row & 7) << 4));
        bfr[ni] = *reinterpret_cast<const short8*>(reinterpret_cast<const char*>(Bs) + byte);
      }
      #pragma unroll
      for (int mi = 0; mi < 4; ++mi)
        #pragma unroll
        for (int ni = 0; ni < 4; ++ni)
          acc[mi][ni] = __builtin_amdgcn_mfma_f32_16x16x32_bf16(af[mi], bfr[ni], acc[mi][ni], 0, 0, 0);
    }
    __syncthreads();
  }

  #pragma unroll
  for (int mi = 0; mi < 4; ++mi) {
    #pragma unroll
    for (int ni = 0; ni < 4; ++ni) {
      #pragma unroll
      for (int r = 0; r < 4; ++r) {
        int row = tm + wm*64 + mi*16 + ((l >> 4) * 4) + r;
        int col = tn + wn*64 + ni*16 + (l & 15);
        float v = acc[mi][ni][r] + bias[col];
        if constexpr (MODE == 1) {
          Cf[(size_t)row * N + col] = v;
        } else {
          int w3 = col >> 9, h = (col >> 6) & 7, hd = col & 63;
          int n = row >> 3, b = row & 7;
          Cq[(size_t)w3 * ((size_t)NH_TOT * NSEQ * HDIM)
             + ((size_t)(b * NHEAD + h) * NSEQ + n) * HDIM + hd] = f2bf(v);
        }
      }
    }
  }
}

// ---------------- Flash attention (swapped QK^T, 32x32 MFMA) ----------------
// Q/K/V: [64 heads][2048][64] bf16. Output Ob: [16384 rows=n*8+b][512=h*64+hd] bf16.
// Per block: 4 waves x 32 q-rows = 128 q. KV tile = 64.
#define CSC 0.18033688011112042f   /* (1/8) * log2(e) */
#define RESCALE_THR 10.0f

__global__ __launch_bounds__(256) void attn_fwd(
    const ushort_t* __restrict__ Qb, const ushort_t* __restrict__ Kb,
    const ushort_t* __restrict__ Vb, ushort_t* __restrict__ Ob)
{
  __shared__ __align__(16) ushort_t Ks[64*64];
  __shared__ __align__(16) ushort_t Vt[64*64];
  const int t = threadIdx.x, w = t >> 6, l = t & 63;
  const int lq = l & 31, h = l >> 5;
  const int bh = blockIdx.y;
  const int qt = blockIdx.x;
  const int b = bh >> 3, hh = bh & 7;
  const size_t hbase = (size_t)bh * NSEQ * HDIM;
  const int qbase = qt*128 + w*32;

  // Q B-fragments (raw, unscaled): Q[q=lq][kd*16 + h*8 .. +8]
  short8 qreg[4];
  #pragma unroll
  for (int kd = 0; kd < 4; ++kd)
    qreg[kd] = *reinterpret_cast<const short8*>(
        Qb + hbase + (size_t)(qbase + lq) * HDIM + kd*16 + h*8);

  float m_run = -3.0e38f, l_run = 0.0f;
  f32x16 Oacc[2] = {};

  const int srow = t >> 3;          // 0..31
  const int scol = (t & 7) * 8;     // 0..56

  for (int kt = 0; kt < NSEQ/64; ++kt) {
    const size_t kvb = hbase + (size_t)kt * 64 * HDIM;
    __syncthreads();  // previous tile's LDS reads done

    // V rows -> regs (issued first so their vmcnt drains before the glls')
    short8 v0 = *reinterpret_cast<const short8*>(Vb + kvb + (size_t)srow*HDIM + scol);
    short8 v1 = *reinterpret_cast<const short8*>(Vb + kvb + (size_t)(srow+32)*HDIM + scol);
    // K -> LDS direct, pre-swizzled source so LDS holds swizzled layout
    {
      int c0 = scol ^ (SW(srow) << 3);
      int c1 = scol ^ (SW(srow + 32) << 3);
      gll16(Kb + kvb + (size_t)srow*HDIM + c0,      Ks + t*8);
      gll16(Kb + kvb + (size_t)(srow+32)*HDIM + c1, Ks + 2048 + t*8);
    }
    // V^T (d-major) swizzled scalar writes
    #pragma unroll
    for (int e = 0; e < 8; ++e) {
      int d = scol + e;
      int sw = SW(d) << 4;
      *reinterpret_cast<ushort_t*>(reinterpret_cast<char*>(Vt) + d*128 + ((srow*2) ^ sw)) = (ushort_t)v0[e];
      *reinterpret_cast<ushort_t*>(reinterpret_cast<char*>(Vt) + d*128 + (((srow+32)*2) ^ sw)) = (ushort_t)v1[e];
    }
    __syncthreads();  // staging complete (drains gll vmcnt too)

    // ---- S^T[kv 64][q 32] = K · Q^T  (2 row-tiles of 32x32, K-dim 64) ----
    f32x16 s0 = {}, s1 = {};
    #pragma unroll
    for (int kd = 0; kd < 4; ++kd) {
      int kv0 = lq;
      short8 kf0 = *reinterpret_cast<const short8*>(
          reinterpret_cast<const char*>(Ks) + kv0*128 + ((kd*32 + h*16) ^ (SW(kv0) << 4)));
      s0 = __builtin_amdgcn_mfma_f32_32x32x16_bf16(kf0, qreg[kd], s0, 0, 0, 0);
      int kv1 = 32 + lq;
      short8 kf1 = *reinterpret_cast<const short8*>(
          reinterpret_cast<const char*>(Ks) + kv1*128 + ((kd*32 + h*16) ^ (SW(kv1) << 4)));
      s1 = __builtin_amdgcn_mfma_f32_32x32x16_bf16(kf1, qreg[kd], s1, 0, 0, 0);
    }

    // ---- online softmax, q = lq per lane ----
    float mx = -3.0e38f;
    #pragma unroll
    for (int r = 0; r < 16; ++r) mx = fmaxf(mx, fmaxf(s0[r], s1[r]));
    mx = fmaxf(mx, __shfl_xor(mx, 32));
    float tmax = mx * CSC;   // scaled log2 domain

    if (__any(tmax - m_run > RESCALE_THR)) {
      float mnew = fmaxf(m_run, tmax);
      float corr = __builtin_amdgcn_exp2f(m_run - mnew);
      l_run *= corr;
      m_run = mnew;
      #pragma unroll
      for (int r = 0; r < 16; ++r) {
        int qrow = (r & 3) + 8*(r >> 2) + 4*h;
        float cr = __shfl(corr, qrow, 64);
        Oacc[0][r] *= cr;
        Oacc[1][r] *= cr;
      }
    }

    float psum = 0.0f;
    #pragma unroll
    for (int r = 0; r < 16; ++r) {
      float a = __builtin_amdgcn_exp2f(fmaf(s0[r], CSC, -m_run));
      float c = __builtin_amdgcn_exp2f(fmaf(s1[r], CSC, -m_run));
      s0[r] = a; s1[r] = c;
      psum += a + c;
    }
    psum += __shfl_xor(psum, 32);
    l_run += psum;

    // ---- pack P to bf16 words, redistribute via permlane32_swap ----
    uint32 w0[8], w1[8];
    #pragma unroll
    for (int i = 0; i < 8; ++i) {
      float a0 = s0[2*i], b0 = s0[2*i+1];
      float a1 = s1[2*i], b1 = s1[2*i+1];
      asm("v_cvt_pk_bf16_f32 %0, %1, %2" : "=v"(w0[i]) : "v"(a0), "v"(b0));
      asm("v_cvt_pk_bf16_f32 %0, %1, %2" : "=v"(w1[i]) : "v"(a1), "v"(b1));
    }
    uint32 pa[4][4];
    #pragma unroll
    for (int sg = 0; sg < 2; ++sg) {
      uint32 a, bb;
      a = w0[4*sg+0]; bb = w0[4*sg+2];
      asm("v_permlane32_swap_b32 %0, %1" : "+v"(a), "+v"(bb));
      pa[sg][0] = a; pa[sg][2] = bb;
      a = w0[4*sg+1]; bb = w0[4*sg+3];
      asm("v_permlane32_swap_b32 %0, %1" : "+v"(a), "+v"(bb));
      pa[sg][1] = a; pa[sg][3] = bb;
      a = w1[4*sg+0]; bb = w1[4*sg+2];
      asm("v_permlane32_swap_b32 %0, %1" : "+v"(a), "+v"(bb));
      pa[2+sg][0] = a; pa[2+sg][2] = bb;
      a = w1[4*sg+1]; bb = w1[4*sg+3];
      asm("v_permlane32_swap_b32 %0, %1" : "+v"(a), "+v"(bb));
      pa[2+sg][1] = a; pa[2+sg][3] = bb;
    }

    // ---- O += P V ----
    #pragma unroll
    for (int km = 0; km < 4; ++km) {
      uint4v u; u[0] = pa[km][0]; u[1] = pa[km][1]; u[2] = pa[km][2]; u[3] = pa[km][3];
      short8 paf = __builtin_bit_cast(short8, u);
      #pragma unroll
      for (int dt = 0; dt < 2; ++dt) {
        int d = dt*32 + lq;
        short8 vf = *reinterpret_cast<const short8*>(
            reinterpret_cast<const char*>(Vt) + d*128 + ((km*32 + h*16) ^ (SW(d) << 4)));
        Oacc[dt] = __builtin_amdgcn_mfma_f32_32x32x16_bf16(paf, vf, Oacc[dt], 0, 0, 0);
      }
    }
  }

  // ---- epilogue: O /= l, write bf16 ----
  float linv = 1.0f / l_run;
  #pragma unroll
  for (int r = 0; r < 16; ++r) {
    int qrow = (r & 3) + 8*(r >> 2) + 4*h;
    float li = __shfl(linv, qrow, 64);
    int n = qbase + qrow;
    #pragma unroll
    for (int dt = 0; dt < 2; ++dt) {
      int d = dt*32 + lq;
      Ob[((size_t)n * BSZ + b) * EMB + hh*64 + d] = f2bf(Oacc[dt][r] * li);
    }
  }
}

extern "C" void kernel_launch(void* const* d_in, const int* in_sizes, int n_in,
                              void* d_out, int out_size, void* d_ws, size_t ws_size,
                              hipStream_t stream) {
  (void)in_sizes; (void)n_in; (void)out_size; (void)ws_size;
  const float* seq  = (const float*)d_in[0];
  const float* Wqkv = (const float*)d_in[1];
  const float* bqkv = (const float*)d_in[2];
  const float* Wout = (const float*)d_in[3];
  const float* bout = (const float*)d_in[4];
  float* out = (float*)d_out;

  ushort_t* seq_bf  = (ushort_t*)d_ws;
  ushort_t* wqkv_bf = seq_bf  + (size_t)MTOK * EMB;
  ushort_t* wout_bf = wqkv_bf + (size_t)3 * EMB * EMB;
  ushort_t* qkvbuf  = wout_bf + (size_t)EMB * EMB;
  ushort_t* attno   = qkvbuf  + (size_t)3 * NH_TOT * NSEQ * HDIM;

  cvt_f32_bf16<<<(MTOK*EMB/4 + 255)/256, 256, 0, stream>>>(seq, seq_bf, MTOK*EMB/4);
  cvt_f32_bf16<<<(3*EMB*EMB/4 + 255)/256, 256, 0, stream>>>(Wqkv, wqkv_bf, 3*EMB*EMB/4);
  cvt_f32_bf16<<<(EMB*EMB/4 + 255)/256, 256, 0, stream>>>(Wout, wout_bf, EMB*EMB/4);

  gemm_bt2<0><<<dim3(12, 128), 256, 0, stream>>>(seq_bf, wqkv_bf, bqkv, nullptr, qkvbuf,
                                                 MTOK, 3*EMB, EMB);

  const ushort_t* Qb = qkvbuf;
  const ushort_t* Kb = qkvbuf + (size_t)NH_TOT * NSEQ * HDIM;
  const ushort_t* Vb = Kb     + (size_t)NH_TOT * NSEQ * HDIM;
  attn_fwd<<<dim3(16, 64), 256, 0, stream>>>(Qb, Kb, Vb, attno);

  gemm_bt2<1><<<dim3(4, 128), 256, 0, stream>>>(attno, wout_bf, bout, out, nullptr,
                                                MTOK, EMB, EMB);
}